// Round 2
// baseline (274.208 us; speedup 1.0000x reference)
//
#include <hip/hip_runtime.h>
#include <hip/hip_bf16.h>

// CapsNet dynamic routing, pred never materialized:
//   prep:  x16[b][c][i], xT16[b][i][c]  (fp16, once)
//   K1: softmax(b) -> c ;  y[b,j,c] = sum_i c[b,j,i] x[b,c,i]   (MFMA fp16)
//   K2: s = W.y + bias*csum ; v = squash(s) ; u = v^T W ; vb = v.bias
//   K3: b += u @ x + vb                                          (MFMA fp16)
// 3 iterations; last stops at v.

#define BSZ 256
#define CDIM 256
#define IDIM 256
#define JDIM 32
#define DDIM 64

typedef _Float16 f16x8 __attribute__((ext_vector_type(8)));
typedef _Float16 f16x4 __attribute__((ext_vector_type(4)));
typedef float f32x4 __attribute__((ext_vector_type(4)));

// ---------------------------------------------------------------------------
// prep: x (f32 [b][c][i]) -> x16 [b][c][i] and xT16 [b][i][c], both fp16.
// grid (BSZ, 2), block 256.
// ---------------------------------------------------------------------------
__global__ __launch_bounds__(256) void prep_cvt(
    const float* __restrict__ x,
    _Float16* __restrict__ x16,
    _Float16* __restrict__ xT16)
{
  const int b = blockIdx.x;
  const int t = threadIdx.x;
  const int ih = blockIdx.y;
  const float* xb = x + (size_t)b * 65536;

  // phase 1: transpose-gather. lane covers one i, 128 c's; loads are
  // row-coalesced (two 512B segments per instr), stores are 16B/lane at
  // 512B stride (L2 write-combines across c0 iterations).
  const int il = t & 127, ch = t >> 7;
  const int i = ih * 128 + il;
  _Float16* xTb = xT16 + (size_t)b * 65536;
  for (int c0 = ch * 128; c0 < ch * 128 + 128; c0 += 8) {
    f16x8 r;
    #pragma unroll
    for (int s = 0; s < 8; ++s) r[s] = (_Float16)xb[(c0 + s) * 256 + i];
    *reinterpret_cast<f16x8*>(&xTb[i * 256 + c0]) = r;
  }

  // phase 2: straight cvt, p-space split across grid.y
  _Float16* x16b = x16 + (size_t)b * 65536;
  for (int p = t + ih * 256; p < 16384; p += 512) {
    int row = p >> 6, cq = (p & 63) * 4;
    float4 v = *reinterpret_cast<const float4*>(&xb[row * 256 + cq]);
    f16x4 h;
    h[0] = (_Float16)v.x; h[1] = (_Float16)v.y;
    h[2] = (_Float16)v.z; h[3] = (_Float16)v.w;
    *reinterpret_cast<f16x4*>(&x16b[row * 256 + cq]) = h;
  }
}

// ---------------------------------------------------------------------------
// K1: softmax over j (per column i) + y[j,c'] = sum_i c[j,i]*x16[c',i]
// grid (BSZ, 2) : blockIdx.y selects c'-half. block 256.
// ---------------------------------------------------------------------------
__global__ __launch_bounds__(256) void k1_softmax_y(
    const _Float16* __restrict__ x16,  // [BSZ][CDIM][IDIM]
    const float* __restrict__ bsrc,    // [BSZ][JDIM][IDIM]
    float* __restrict__ y_ws,          // [BSZ][JDIM][CDIM]
    float* __restrict__ csum_ws)       // [BSZ][JDIM]
{
  __shared__ __align__(16) _Float16 cs[JDIM * 264];
  const int b = blockIdx.x;
  const int t = threadIdx.x;

  {
    const float* bp = bsrc + (size_t)b * (JDIM * IDIM) + t;
    float bv[JDIM];
    #pragma unroll
    for (int j = 0; j < JDIM; ++j) bv[j] = bp[j * IDIM];
    float m = bv[0];
    #pragma unroll
    for (int j = 1; j < JDIM; ++j) m = fmaxf(m, bv[j]);
    float s = 0.f;
    #pragma unroll
    for (int j = 0; j < JDIM; ++j) { bv[j] = __expf(bv[j] - m); s += bv[j]; }
    float r = 1.f / s;
    #pragma unroll
    for (int j = 0; j < JDIM; ++j) cs[j * 264 + t] = (_Float16)(bv[j] * r);
  }
  __syncthreads();

  // csum[j]: 8 threads per j, 32 i's each (vectorized), shfl-reduce
  if (blockIdx.y == 0) {
    const int j = t >> 3, ig = t & 7;
    float su = 0.f;
    #pragma unroll
    for (int s8 = 0; s8 < 32; s8 += 8) {
      f16x8 vv = *reinterpret_cast<const f16x8*>(&cs[j * 264 + ig * 32 + s8]);
      #pragma unroll
      for (int k = 0; k < 8; ++k) su += (float)vv[k];
    }
    su += __shfl_xor(su, 1);
    su += __shfl_xor(su, 2);
    su += __shfl_xor(su, 4);
    if (ig == 0) csum_ws[b * JDIM + j] = su;
  }

  const int w = t >> 6, lane = t & 63, l15 = lane & 15, quad = lane >> 4;
  const int cbase = blockIdx.y * 128 + w * 32;
  const _Float16* xb = x16 + (size_t)b * 65536;

  f32x4 acc[2][2];
  #pragma unroll
  for (int mt = 0; mt < 2; ++mt)
    #pragma unroll
    for (int nt = 0; nt < 2; ++nt)
      acc[mt][nt] = (f32x4){0.f, 0.f, 0.f, 0.f};

  for (int k0 = 0; k0 < IDIM; k0 += 32) {
    const int ko = k0 + quad * 8;
    f16x8 a0 = *reinterpret_cast<const f16x8*>(&cs[l15 * 264 + ko]);
    f16x8 a1 = *reinterpret_cast<const f16x8*>(&cs[(16 + l15) * 264 + ko]);
    #pragma unroll
    for (int nt = 0; nt < 2; ++nt) {
      const int cp = cbase + nt * 16 + l15;
      f16x8 bf = *reinterpret_cast<const f16x8*>(&xb[cp * 256 + ko]);
      acc[0][nt] = __builtin_amdgcn_mfma_f32_16x16x32_f16(a0, bf, acc[0][nt], 0, 0, 0);
      acc[1][nt] = __builtin_amdgcn_mfma_f32_16x16x32_f16(a1, bf, acc[1][nt], 0, 0, 0);
    }
  }

  float* yb = y_ws + (size_t)b * (JDIM * CDIM);
  #pragma unroll
  for (int mt = 0; mt < 2; ++mt)
    #pragma unroll
    for (int nt = 0; nt < 2; ++nt) {
      const int cp = cbase + nt * 16 + l15;
      #pragma unroll
      for (int rr = 0; rr < 4; ++rr) {
        const int j = mt * 16 + quad * 4 + rr;
        yb[j * CDIM + cp] = acc[mt][nt][rr];
      }
    }
}

// ---------------------------------------------------------------------------
// K2: s = W_j . y + bias*csum ; v = squash(s) ; u = v^T W_j ; vb = v.bias
// grid 1024 = 32 j * 32 chunks of 8 batches. block 256.
// ---------------------------------------------------------------------------
__global__ __launch_bounds__(256) void k2_route(
    const float* __restrict__ W,
    const float* __restrict__ bias,
    const float* __restrict__ y_ws,
    const float* __restrict__ csum_ws,
    _Float16* __restrict__ u16,
    float* __restrict__ vb_ws,
    float* __restrict__ vout,
    int final_iter)
{
  __shared__ __align__(16) float Wj[DDIM * 260];
  __shared__ __align__(16) float ysh[8 * 256];
  __shared__ __align__(16) float vsh[8 * 64];
  __shared__ float bjs[DDIM];
  __shared__ float csums[8];
  const int jb = blockIdx.x & 31;
  const int b0 = (blockIdx.x >> 5) * 8;
  const int t = threadIdx.x;

  for (int p = t; p < DDIM * 64; p += 256) {
    int d = p >> 6, cq = p & 63;
    *reinterpret_cast<float4*>(&Wj[d * 260 + cq * 4]) =
        *reinterpret_cast<const float4*>(&W[(size_t)(jb * DDIM + d) * CDIM + cq * 4]);
  }
  for (int p = t; p < 8 * 64; p += 256) {
    int bs_ = p >> 6, cq = p & 63;
    *reinterpret_cast<float4*>(&ysh[bs_ * 256 + cq * 4]) =
        *reinterpret_cast<const float4*>(&y_ws[((size_t)(b0 + bs_) * JDIM + jb) * CDIM + cq * 4]);
  }
  if (t < DDIM) bjs[t] = bias[jb * DDIM + t];
  if (t < 8)    csums[t] = csum_ws[(b0 + t) * JDIM + jb];
  __syncthreads();

  const int bs = t >> 5;
  const int dd = t & 31;
  float s0 = 0.f, s1 = 0.f;
  const float* yr  = &ysh[bs * 256];
  const float* w0p = &Wj[dd * 260];
  const float* w1p = &Wj[(dd + 32) * 260];
  for (int c = 0; c < CDIM; c += 4) {
    float4 yv = *reinterpret_cast<const float4*>(&yr[c]);
    float4 wa = *reinterpret_cast<const float4*>(&w0p[c]);
    float4 wb = *reinterpret_cast<const float4*>(&w1p[c]);
    s0 += yv.x * wa.x + yv.y * wa.y + yv.z * wa.z + yv.w * wa.w;
    s1 += yv.x * wb.x + yv.y * wb.y + yv.z * wb.z + yv.w * wb.w;
  }
  float cz = csums[bs];
  s0 += bjs[dd] * cz;
  s1 += bjs[dd + 32] * cz;

  float n2 = s0 * s0 + s1 * s1;
  n2 += __shfl_xor(n2, 16, 32);
  n2 += __shfl_xor(n2, 8, 32);
  n2 += __shfl_xor(n2, 4, 32);
  n2 += __shfl_xor(n2, 2, 32);
  n2 += __shfl_xor(n2, 1, 32);
  float nrm = sqrtf(n2);
  float sc = nrm / (1.f + n2);
  float v0 = s0 * sc, v1 = s1 * sc;

  if (final_iter) {
    float* vp = vout + ((size_t)(b0 + bs) * JDIM + jb) * DDIM;
    vp[dd] = v0;
    vp[dd + 32] = v1;
  } else {
    vsh[bs * 64 + dd] = v0;
    vsh[bs * 64 + dd + 32] = v1;
    float vb = v0 * bjs[dd] + v1 * bjs[dd + 32];
    vb += __shfl_xor(vb, 16, 32);
    vb += __shfl_xor(vb, 8, 32);
    vb += __shfl_xor(vb, 4, 32);
    vb += __shfl_xor(vb, 2, 32);
    vb += __shfl_xor(vb, 1, 32);
    if (dd == 0) vb_ws[(b0 + bs) * JDIM + jb] = vb;
    __syncthreads();

    float ua[8] = {0.f, 0.f, 0.f, 0.f, 0.f, 0.f, 0.f, 0.f};
    for (int d0 = 0; d0 < DDIM; d0 += 4) {
      float q0 = Wj[(d0 + 0) * 260 + t];
      float q1 = Wj[(d0 + 1) * 260 + t];
      float q2 = Wj[(d0 + 2) * 260 + t];
      float q3 = Wj[(d0 + 3) * 260 + t];
      #pragma unroll
      for (int k = 0; k < 8; ++k) {
        float4 vv = *reinterpret_cast<const float4*>(&vsh[k * 64 + d0]);
        ua[k] += vv.x * q0 + vv.y * q1 + vv.z * q2 + vv.w * q3;
      }
    }
    #pragma unroll
    for (int k = 0; k < 8; ++k)
      u16[((size_t)(b0 + k) * JDIM + jb) * CDIM + t] = (_Float16)ua[k];
  }
}

// ---------------------------------------------------------------------------
// K3: b_new[j,i] = b_old[j,i] + sum_c u[j,c]*xT16[i,c] + vb[j]
// grid (BSZ, 2) : blockIdx.y selects i-half. block 256.
// ---------------------------------------------------------------------------
__global__ __launch_bounds__(256) void k3_delta(
    const _Float16* __restrict__ xT16,  // [BSZ][IDIM][CDIM]
    const _Float16* __restrict__ u16,   // [BSZ][JDIM][CDIM]
    const float* __restrict__ vb_ws,
    const float* __restrict__ bsrc,
    float* __restrict__ bdst)
{
  __shared__ __align__(16) _Float16 us[JDIM * 264];
  __shared__ float vbs[JDIM];
  const int b = blockIdx.x;
  const int t = threadIdx.x;

  const int* ug = reinterpret_cast<const int*>(u16 + (size_t)b * (JDIM * CDIM));
  for (int p = t; p < 4096; p += 256) {
    int j = p >> 7, c2 = p & 127;
    *reinterpret_cast<int*>(&us[j * 264 + c2 * 2]) = ug[p];
  }
  if (t < JDIM) vbs[t] = vb_ws[b * JDIM + t];
  __syncthreads();

  const int w = t >> 6, lane = t & 63, l15 = lane & 15, quad = lane >> 4;
  const int ibase = blockIdx.y * 128 + w * 32;
  const _Float16* xb = xT16 + (size_t)b * 65536;

  f32x4 acc[2][2];
  #pragma unroll
  for (int mt = 0; mt < 2; ++mt)
    #pragma unroll
    for (int nt = 0; nt < 2; ++nt)
      acc[mt][nt] = (f32x4){0.f, 0.f, 0.f, 0.f};

  for (int k0 = 0; k0 < CDIM; k0 += 32) {
    const int ko = k0 + quad * 8;
    f16x8 a0 = *reinterpret_cast<const f16x8*>(&us[l15 * 264 + ko]);
    f16x8 a1 = *reinterpret_cast<const f16x8*>(&us[(16 + l15) * 264 + ko]);
    #pragma unroll
    for (int nt = 0; nt < 2; ++nt) {
      const int ii = ibase + nt * 16 + l15;
      f16x8 bf = *reinterpret_cast<const f16x8*>(&xb[ii * 256 + ko]);
      acc[0][nt] = __builtin_amdgcn_mfma_f32_16x16x32_f16(a0, bf, acc[0][nt], 0, 0, 0);
      acc[1][nt] = __builtin_amdgcn_mfma_f32_16x16x32_f16(a1, bf, acc[1][nt], 0, 0, 0);
    }
  }

  const float* bsb = bsrc + (size_t)b * (JDIM * IDIM);
  float* bdb = bdst + (size_t)b * (JDIM * IDIM);
  #pragma unroll
  for (int mt = 0; mt < 2; ++mt)
    #pragma unroll
    for (int nt = 0; nt < 2; ++nt) {
      const int ii = ibase + nt * 16 + l15;
      #pragma unroll
      for (int rr = 0; rr < 4; ++rr) {
        const int j = mt * 16 + quad * 4 + rr;
        const int idx = j * IDIM + ii;
        bdb[idx] = bsb[idx] + acc[mt][nt][rr] + vbs[j];
      }
    }
}

// ---------------------------------------------------------------------------
extern "C" void kernel_launch(void* const* d_in, const int* in_sizes, int n_in,
                              void* d_out, int out_size, void* d_ws, size_t ws_size,
                              hipStream_t stream) {
  (void)in_sizes; (void)n_in; (void)out_size; (void)ws_size;
  const float* x      = (const float*)d_in[0];
  const float* W      = (const float*)d_in[1];
  const float* bias   = (const float*)d_in[2];
  const float* b_init = (const float*)d_in[3];
  char* ws = (char*)d_ws;

  _Float16* x16     = (_Float16*)(ws);                           // 32 MiB
  _Float16* xT16    = (_Float16*)(ws + (32u << 20));             // 32 MiB
  float*    y_ws    = (float*)(ws + (64u << 20));                // 8 MiB
  _Float16* u16     = (_Float16*)(ws + (72u << 20));             // 4 MiB
  float*    b_ws    = (float*)(ws + (80u << 20));                // 8 MiB
  float*    csum_ws = (float*)(ws + (88u << 20));                // 32 KiB
  float*    vb_ws   = (float*)(ws + (88u << 20) + (32u << 10));  // 32 KiB
  float*    vout    = (float*)d_out;

  dim3 g12(BSZ, 2);

  prep_cvt<<<g12, 256, 0, stream>>>(x, x16, xT16);
  // iter 1
  k1_softmax_y<<<g12, 256, 0, stream>>>(x16, b_init, y_ws, csum_ws);
  k2_route<<<1024, 256, 0, stream>>>(W, bias, y_ws, csum_ws, u16, vb_ws, vout, 0);
  k3_delta<<<g12, 256, 0, stream>>>(xT16, u16, vb_ws, b_init, b_ws);
  // iter 2
  k1_softmax_y<<<g12, 256, 0, stream>>>(x16, b_ws, y_ws, csum_ws);
  k2_route<<<1024, 256, 0, stream>>>(W, bias, y_ws, csum_ws, u16, vb_ws, vout, 0);
  k3_delta<<<g12, 256, 0, stream>>>(xT16, u16, vb_ws, b_ws, b_ws);
  // iter 3
  k1_softmax_y<<<g12, 256, 0, stream>>>(x16, b_ws, y_ws, csum_ws);
  k2_route<<<1024, 256, 0, stream>>>(W, bias, y_ws, csum_ws, u16, vb_ws, vout, 1);
}

// Round 3
// 219.805 us; speedup vs baseline: 1.2475x; 1.2475x over previous
//
#include <hip/hip_runtime.h>
#include <hip/hip_bf16.h>

// CapsNet dynamic routing, pred never materialized.
//   prep:  x16[b][c][i], xT16[b][i][c]  (fp16, register 4x4 transpose)
//   K31:   [delta = u@x (MFMA) -> b update] -> softmax -> y = c@x^T (MFMA)
//   K2:    s = W.y + bias*csum ; v = squash(s) ; u = v^T W ; vb = v.bias
// 3 iterations: K31(m0),K2 | K31(m1),K2 | K31(m2),K2(final->v)

#define BSZ 256
#define CDIM 256
#define IDIM 256
#define JDIM 32
#define DDIM 64

typedef _Float16 f16x8 __attribute__((ext_vector_type(8)));
typedef _Float16 f16x4 __attribute__((ext_vector_type(4)));
typedef float f32x4 __attribute__((ext_vector_type(4)));

// ---------------------------------------------------------------------------
// prep: x fp32 [b][c][i] -> x16 [b][c][i] + xT16 [b][i][c], fp16.
// grid (BSZ, 8), block 256. Register 4x4 transpose, x read exactly once.
// ---------------------------------------------------------------------------
__global__ __launch_bounds__(256) void prep_cvt(
    const float* __restrict__ x,
    _Float16* __restrict__ x16,
    _Float16* __restrict__ xT16)
{
  const int b = blockIdx.x;
  const int c0 = blockIdx.y * 32;
  const int t = threadIdx.x;
  const float* xb = x + (size_t)b * 65536;
  _Float16* x16b = x16 + (size_t)b * 65536;
  _Float16* xTb  = xT16 + (size_t)b * 65536;

  #pragma unroll
  for (int q = 0; q < 2; ++q) {
    const int tile = q * 256 + t;            // 0..511
    const int c4 = (tile & 7) * 4;           // 0..28
    const int i4 = (tile >> 3) * 4;          // 0..252
    f32x4 v[4];
    #pragma unroll
    for (int s = 0; s < 4; ++s)
      v[s] = *reinterpret_cast<const f32x4*>(&xb[(c0 + c4 + s) * 256 + i4]);
    // straight cvt rows -> x16
    #pragma unroll
    for (int s = 0; s < 4; ++s) {
      f16x4 h;
      h[0] = (_Float16)v[s][0]; h[1] = (_Float16)v[s][1];
      h[2] = (_Float16)v[s][2]; h[3] = (_Float16)v[s][3];
      *reinterpret_cast<f16x4*>(&x16b[(c0 + c4 + s) * 256 + i4]) = h;
    }
    // 4x4 register transpose -> xT16
    #pragma unroll
    for (int m = 0; m < 4; ++m) {
      f16x4 h;
      h[0] = (_Float16)v[0][m]; h[1] = (_Float16)v[1][m];
      h[2] = (_Float16)v[2][m]; h[3] = (_Float16)v[3][m];
      *reinterpret_cast<f16x4*>(&xTb[(i4 + m) * 256 + c0 + c4]) = h;
    }
  }
}

// ---------------------------------------------------------------------------
// K31: fused delta + b-update + softmax + y.
// grid BSZ, block 512 (8 waves: wave w owns 32 i-cols in phase A, 32 c-cols
// in phase B). mode: 0 = no delta (softmax from bsrc), 1 = delta + store b,
// 2 = delta, no b store.
// ---------------------------------------------------------------------------
__global__ __launch_bounds__(512) void k31_fused(
    const _Float16* __restrict__ x16,   // [BSZ][CDIM][IDIM]
    const _Float16* __restrict__ xT16,  // [BSZ][IDIM][CDIM]
    const _Float16* __restrict__ u16,   // [BSZ][JDIM][CDIM]
    const float* __restrict__ vb_ws,    // [BSZ][JDIM]
    const float* __restrict__ bsrc,     // [BSZ][JDIM][IDIM]
    float* __restrict__ bdst,           // [BSZ][JDIM][IDIM] (mode 1)
    float* __restrict__ y_ws,           // [BSZ][JDIM][CDIM]
    float* __restrict__ csum_ws,        // [BSZ][JDIM]
    int mode)
{
  __shared__ __align__(16) _Float16 us[JDIM * 264];
  __shared__ __align__(16) _Float16 cs[JDIM * 264];
  __shared__ __align__(16) float bsh[JDIM * 264];
  __shared__ float vbs[JDIM];
  const int b = blockIdx.x;
  const int t = threadIdx.x;
  const int w = t >> 6, lane = t & 63, l15 = lane & 15, quad = lane >> 4;

  if (mode) {
    // stage u16 -> LDS
    const int* ug = reinterpret_cast<const int*>(u16 + (size_t)b * (JDIM * CDIM));
    for (int p = t; p < 4096; p += 512) {
      int j = p >> 7, c2 = p & 127;
      *reinterpret_cast<int*>(&us[j * 264 + c2 * 2]) = ug[p];
    }
    if (t < JDIM) vbs[t] = vb_ws[b * JDIM + t];
    __syncthreads();

    // delta[j, i] = sum_c us[j][c] * xT16[i][c]
    const _Float16* xTb = xT16 + (size_t)b * 65536;
    f32x4 acc[2][2];
    #pragma unroll
    for (int mt = 0; mt < 2; ++mt)
      #pragma unroll
      for (int nt = 0; nt < 2; ++nt) acc[mt][nt] = (f32x4){0.f, 0.f, 0.f, 0.f};
    const int ibase = w * 32;
    for (int k0 = 0; k0 < CDIM; k0 += 32) {
      const int ko = k0 + quad * 8;
      f16x8 a0 = *reinterpret_cast<const f16x8*>(&us[l15 * 264 + ko]);
      f16x8 a1 = *reinterpret_cast<const f16x8*>(&us[(16 + l15) * 264 + ko]);
      #pragma unroll
      for (int nt = 0; nt < 2; ++nt) {
        const int ii = ibase + nt * 16 + l15;
        f16x8 bf = *reinterpret_cast<const f16x8*>(&xTb[ii * 256 + ko]);
        acc[0][nt] = __builtin_amdgcn_mfma_f32_16x16x32_f16(a0, bf, acc[0][nt], 0, 0, 0);
        acc[1][nt] = __builtin_amdgcn_mfma_f32_16x16x32_f16(a1, bf, acc[1][nt], 0, 0, 0);
      }
    }
    // b_new = b_old + delta + vb  -> bsh (and optionally global)
    const float* bsb = bsrc + (size_t)b * (JDIM * IDIM);
    float* bdb = bdst + (size_t)b * (JDIM * IDIM);
    #pragma unroll
    for (int mt = 0; mt < 2; ++mt)
      #pragma unroll
      for (int nt = 0; nt < 2; ++nt) {
        const int ii = ibase + nt * 16 + l15;
        #pragma unroll
        for (int rr = 0; rr < 4; ++rr) {
          const int j = mt * 16 + quad * 4 + rr;
          float bn = bsb[j * IDIM + ii] + acc[mt][nt][rr] + vbs[j];
          bsh[j * 264 + ii] = bn;
          if (mode == 1) bdb[j * IDIM + ii] = bn;
        }
      }
    __syncthreads();
  }

  // softmax over j, one column i per thread (t < 256)
  if (t < 256) {
    float bv[JDIM];
    if (mode) {
      #pragma unroll
      for (int j = 0; j < JDIM; ++j) bv[j] = bsh[j * 264 + t];
    } else {
      const float* bp = bsrc + (size_t)b * (JDIM * IDIM) + t;
      #pragma unroll
      for (int j = 0; j < JDIM; ++j) bv[j] = bp[j * IDIM];
    }
    float m = bv[0];
    #pragma unroll
    for (int j = 1; j < JDIM; ++j) m = fmaxf(m, bv[j]);
    float s = 0.f;
    #pragma unroll
    for (int j = 0; j < JDIM; ++j) { bv[j] = __expf(bv[j] - m); s += bv[j]; }
    float r = 1.f / s;
    #pragma unroll
    for (int j = 0; j < JDIM; ++j) cs[j * 264 + t] = (_Float16)(bv[j] * r);
  }
  __syncthreads();

  // csum[j] = sum_i c[j][i]
  if (t < 256) {
    const int j = t >> 3, ig = t & 7;
    float su = 0.f;
    #pragma unroll
    for (int s8 = 0; s8 < 32; s8 += 8) {
      f16x8 vv = *reinterpret_cast<const f16x8*>(&cs[j * 264 + ig * 32 + s8]);
      #pragma unroll
      for (int k = 0; k < 8; ++k) su += (float)vv[k];
    }
    su += __shfl_xor(su, 1);
    su += __shfl_xor(su, 2);
    su += __shfl_xor(su, 4);
    if (ig == 0) csum_ws[b * JDIM + j] = su;
  }

  // y[j, c] = sum_i cs[j][i] * x16[c][i]
  const _Float16* xb = x16 + (size_t)b * 65536;
  f32x4 acy[2][2];
  #pragma unroll
  for (int mt = 0; mt < 2; ++mt)
    #pragma unroll
    for (int nt = 0; nt < 2; ++nt) acy[mt][nt] = (f32x4){0.f, 0.f, 0.f, 0.f};
  const int cbase = w * 32;
  for (int k0 = 0; k0 < IDIM; k0 += 32) {
    const int ko = k0 + quad * 8;
    f16x8 a0 = *reinterpret_cast<const f16x8*>(&cs[l15 * 264 + ko]);
    f16x8 a1 = *reinterpret_cast<const f16x8*>(&cs[(16 + l15) * 264 + ko]);
    #pragma unroll
    for (int nt = 0; nt < 2; ++nt) {
      const int cp = cbase + nt * 16 + l15;
      f16x8 bf = *reinterpret_cast<const f16x8*>(&xb[cp * 256 + ko]);
      acy[0][nt] = __builtin_amdgcn_mfma_f32_16x16x32_f16(a0, bf, acy[0][nt], 0, 0, 0);
      acy[1][nt] = __builtin_amdgcn_mfma_f32_16x16x32_f16(a1, bf, acy[1][nt], 0, 0, 0);
    }
  }
  float* yb = y_ws + (size_t)b * (JDIM * CDIM);
  #pragma unroll
  for (int mt = 0; mt < 2; ++mt)
    #pragma unroll
    for (int nt = 0; nt < 2; ++nt) {
      const int cp = cbase + nt * 16 + l15;
      #pragma unroll
      for (int rr = 0; rr < 4; ++rr) {
        const int j = mt * 16 + quad * 4 + rr;
        yb[j * CDIM + cp] = acy[mt][nt][rr];
      }
    }
}

// ---------------------------------------------------------------------------
// K2: s = W_j.y + bias*csum ; v = squash ; u = v^T W_j ; vb = v.bias
// grid 256 = 32 j * 8 chunks of 32 batches. block 512.
// Thread (bs = t>>4, dg = t&15) handles d = dg + 16k, k=0..3 (conflict-free).
// ---------------------------------------------------------------------------
__global__ __launch_bounds__(512) void k2_route(
    const float* __restrict__ W,
    const float* __restrict__ bias,
    const float* __restrict__ y_ws,
    const float* __restrict__ csum_ws,
    _Float16* __restrict__ u16,
    float* __restrict__ vb_ws,
    float* __restrict__ vout,
    int final_iter)
{
  __shared__ __align__(16) float Wj[DDIM * 260];
  __shared__ __align__(16) float ysh[32 * 260];
  __shared__ __align__(16) float vsh[32 * 68];
  __shared__ float bjs[DDIM];
  __shared__ float csums[32];
  const int jb = blockIdx.x & 31;
  const int b0 = (blockIdx.x >> 5) * 32;
  const int t = threadIdx.x;

  for (int p = t; p < 4096; p += 512) {          // W_j: 64 rows x 64 float4
    int d = p >> 6, cq = (p & 63) * 4;
    *reinterpret_cast<f32x4*>(&Wj[d * 260 + cq]) =
        *reinterpret_cast<const f32x4*>(&W[(size_t)(jb * DDIM + d) * CDIM + cq]);
  }
  for (int p = t; p < 2048; p += 512) {          // y: 32 rows x 64 float4
    int bs_ = p >> 6, cq = (p & 63) * 4;
    *reinterpret_cast<f32x4*>(&ysh[bs_ * 260 + cq]) =
        *reinterpret_cast<const f32x4*>(&y_ws[((size_t)(b0 + bs_) * JDIM + jb) * CDIM + cq]);
  }
  if (t < DDIM) bjs[t] = bias[jb * DDIM + t];
  if (t < 32)   csums[t] = csum_ws[(b0 + t) * JDIM + jb];
  __syncthreads();

  const int bs = t >> 4;    // 0..31
  const int dg = t & 15;    // handles d = dg + 16k
  float sv[4] = {0.f, 0.f, 0.f, 0.f};
  const float* yr = &ysh[bs * 260];
  for (int c = 0; c < CDIM; c += 4) {
    f32x4 yv = *reinterpret_cast<const f32x4*>(&yr[c]);
    #pragma unroll
    for (int k = 0; k < 4; ++k) {
      f32x4 wv = *reinterpret_cast<const f32x4*>(&Wj[(dg + 16 * k) * 260 + c]);
      sv[k] += yv[0] * wv[0] + yv[1] * wv[1] + yv[2] * wv[2] + yv[3] * wv[3];
    }
  }
  const float cz = csums[bs];
  #pragma unroll
  for (int k = 0; k < 4; ++k) sv[k] += bjs[dg + 16 * k] * cz;

  float n2 = sv[0]*sv[0] + sv[1]*sv[1] + sv[2]*sv[2] + sv[3]*sv[3];
  n2 += __shfl_xor(n2, 1);
  n2 += __shfl_xor(n2, 2);
  n2 += __shfl_xor(n2, 4);
  n2 += __shfl_xor(n2, 8);
  const float nrm = sqrtf(n2);
  const float sc = nrm / (1.f + n2);
  float vv[4];
  #pragma unroll
  for (int k = 0; k < 4; ++k) vv[k] = sv[k] * sc;

  if (final_iter) {
    float* vp = vout + ((size_t)(b0 + bs) * JDIM + jb) * DDIM;
    #pragma unroll
    for (int k = 0; k < 4; ++k) vp[dg + 16 * k] = vv[k];
  } else {
    #pragma unroll
    for (int k = 0; k < 4; ++k) vsh[bs * 68 + dg + 16 * k] = vv[k];
    float vb = 0.f;
    #pragma unroll
    for (int k = 0; k < 4; ++k) vb += vv[k] * bjs[dg + 16 * k];
    vb += __shfl_xor(vb, 1);
    vb += __shfl_xor(vb, 2);
    vb += __shfl_xor(vb, 4);
    vb += __shfl_xor(vb, 8);
    if (dg == 0) vb_ws[(b0 + bs) * JDIM + jb] = vb;
    __syncthreads();

    // u[b_local][c] = sum_d v[b_local][d] * Wj[d][c]; 512 thr = 256 c x 2 halves
    const int c = t & 255;
    const int kh = (t >> 8) * 16;
    float ua[16];
    #pragma unroll
    for (int k = 0; k < 16; ++k) ua[k] = 0.f;
    for (int d0 = 0; d0 < DDIM; d0 += 2) {
      const float q0 = Wj[d0 * 260 + c];
      const float q1 = Wj[(d0 + 1) * 260 + c];
      #pragma unroll
      for (int k = 0; k < 16; ++k)
        ua[k] += vsh[(kh + k) * 68 + d0] * q0 + vsh[(kh + k) * 68 + d0 + 1] * q1;
    }
    #pragma unroll
    for (int k = 0; k < 16; ++k)
      u16[((size_t)(b0 + kh + k) * JDIM + jb) * CDIM + c] = (_Float16)ua[k];
  }
}

// ---------------------------------------------------------------------------
extern "C" void kernel_launch(void* const* d_in, const int* in_sizes, int n_in,
                              void* d_out, int out_size, void* d_ws, size_t ws_size,
                              hipStream_t stream) {
  (void)in_sizes; (void)n_in; (void)out_size; (void)ws_size;
  const float* x      = (const float*)d_in[0];
  const float* W      = (const float*)d_in[1];
  const float* bias   = (const float*)d_in[2];
  const float* b_init = (const float*)d_in[3];
  char* ws = (char*)d_ws;

  _Float16* x16     = (_Float16*)(ws);                           // 32 MiB
  _Float16* xT16    = (_Float16*)(ws + (32u << 20));             // 32 MiB
  float*    y_ws    = (float*)(ws + (64u << 20));                // 8 MiB
  _Float16* u16     = (_Float16*)(ws + (72u << 20));             // 4 MiB
  float*    b_ws    = (float*)(ws + (76u << 20));                // 8 MiB
  float*    csum_ws = (float*)(ws + (84u << 20));                // 32 KiB
  float*    vb_ws   = (float*)(ws + (84u << 20) + (32u << 10));  // 32 KiB
  float*    vout    = (float*)d_out;

  prep_cvt<<<dim3(BSZ, 8), 256, 0, stream>>>(x, x16, xT16);
  // iter 1 (mode 0: b = b_init, no delta)
  k31_fused<<<BSZ, 512, 0, stream>>>(x16, xT16, u16, vb_ws, b_init, b_ws, y_ws, csum_ws, 0);
  k2_route<<<256, 512, 0, stream>>>(W, bias, y_ws, csum_ws, u16, vb_ws, vout, 0);
  // iter 2 (mode 1: delta from b_init, store b2)
  k31_fused<<<BSZ, 512, 0, stream>>>(x16, xT16, u16, vb_ws, b_init, b_ws, y_ws, csum_ws, 1);
  k2_route<<<256, 512, 0, stream>>>(W, bias, y_ws, csum_ws, u16, vb_ws, vout, 0);
  // iter 3 (mode 2: delta from b2, no store)
  k31_fused<<<BSZ, 512, 0, stream>>>(x16, xT16, u16, vb_ws, b_ws, b_ws, y_ws, csum_ws, 2);
  k2_route<<<256, 512, 0, stream>>>(W, bias, y_ws, csum_ws, u16, vb_ws, vout, 1);
}